// Round 3
// baseline (91.295 us; speedup 1.0000x reference)
//
#include <hip/hip_runtime.h>
#include <hip/hip_bf16.h>
#include <math.h>

// Problem constants (fixed by reference setup_inputs)
#define BHALF 4096          // B
#define NROW 8192           // 2B
#define DIM 128             // D
#define NCHUNK 16           // col chunks (16 chunks x 512 cols)
#define INV_T 10.0f         // 1/temperature
#define K1 14.4269504088896f  // INV_T*log2(e): exp((v-1)*10) = 2^(v*K1 - K1)

typedef short bf16x8 __attribute__((ext_vector_type(8)));   // 8 bf16 = 4 VGPRs
typedef float f32x4  __attribute__((ext_vector_type(4)));   // C/D frag

typedef const __attribute__((address_space(1))) void ga_void;
typedef __attribute__((address_space(3))) void ls_void;

// ---------------------------------------------------------------------------
// Kernel 1: row-normalize concat(view1, view2) -> e_bf16 (NROW x DIM);
// zero d_out. One wave per row.
// ---------------------------------------------------------------------------
__global__ __launch_bounds__(256) void normalize_kernel(
    const float* __restrict__ v1, const float* __restrict__ v2,
    __hip_bfloat16* __restrict__ e, float* __restrict__ out) {
  int row  = blockIdx.x * 4 + (threadIdx.x >> 6);
  int lane = threadIdx.x & 63;
  const float* src = (row < BHALF) ? (v1 + (size_t)row * DIM)
                                   : (v2 + (size_t)(row - BHALF) * DIM);
  float2 x = ((const float2*)src)[lane];
  float ss = x.x * x.x + x.y * x.y;
#pragma unroll
  for (int off = 32; off > 0; off >>= 1) ss += __shfl_down(ss, off);
  ss = __shfl(ss, 0);
  float s = 1.0f / fmaxf(sqrtf(ss), 1e-8f);
  ((__hip_bfloat162*)(e + (size_t)row * DIM))[lane] =
      __float22bfloat162_rn(make_float2(x.x * s, x.y * s));
  if (blockIdx.x == 0 && threadIdx.x == 0) out[0] = 0.0f;
}

// ---------------------------------------------------------------------------
// Stage one 128-col strip of e (128 rows x 256 B) into LDS via
// global_load_lds(16B). LDS layout: [128 rows][16 chunks of 16B], chunk index
// XOR-swizzled by (row&7): ds_read_b128 of a fixed global chunk across rows
// spreads over 8 bank-quads. Rule #21: LDS dest LINEAR (wave-uniform base +
// lane*16); swizzle applied by permuting the per-lane GLOBAL source chunk
// (XOR involution). Each wave stages 32 rows.
// ---------------------------------------------------------------------------
__device__ __forceinline__ void stage_strip(const ushort* __restrict__ eC,
                                            ushort* BsBuf, int wave, int lane) {
#pragma unroll
  for (int j = 0; j < 8; ++j) {
    const int row    = wave * 32 + j * 4 + (lane >> 4);
    const int chunkp = lane & 15;                 // LDS chunk this lane fills
    const int gchunk = chunkp ^ (row & 7);        // global chunk it must hold
    const ushort* g  = eC + row * DIM + gchunk * 8;
    ushort* l        = BsBuf + (wave * 32 + j * 4) * 128;  // wave-uniform base
    __builtin_amdgcn_global_load_lds((ga_void*)g, (ls_void*)l, 16, 0, 0);
  }
}

// ---------------------------------------------------------------------------
// MFMA sweep of one 128-col strip vs this wave's 64 rows (4 row-frags).
// MODE 0: diagonal strip (cols within block's row range): mask gr==gc.
// MODE 1: plain strip.
// MODE 2: partner strip: gc == gr^4096 -> positive, store posv[gr].
// Each ds_read_b128 of a B fragment feeds 16 MFMAs (4 row-frags) — R8's
// halving of the LDS-read pipe vs 32-rows/wave.
// ---------------------------------------------------------------------------
template <int MODE>
__device__ __forceinline__ void sweep_strip(
    const ushort* __restrict__ Bs, const bf16x8 (&a_frag)[4][4],
    float (&rsum)[4][4], float* __restrict__ posv, const int (&chunkOff)[4],
    int n, int quad, int rowWave, int colBase) {
#pragma unroll 1
  for (int sub = 0; sub < 8; ++sub) {
    const ushort* bp = Bs + (sub * 16 + n) * 128;
    bf16x8 b[4];
#pragma unroll
    for (int kk = 0; kk < 4; ++kk) b[kk] = *(const bf16x8*)(bp + chunkOff[kk]);
    const int gc = colBase + sub * 16 + n;
#pragma unroll
    for (int rf = 0; rf < 4; ++rf) {
      f32x4 acc = {0.f, 0.f, 0.f, 0.f};
#pragma unroll
      for (int kk = 0; kk < 4; ++kk)
        acc = __builtin_amdgcn_mfma_f32_16x16x32_bf16(a_frag[rf][kk], b[kk],
                                                      acc, 0, 0, 0);
      // C layout: row = quad*4 + reg, col = lane&15 (m89/m91 verified).
#pragma unroll
      for (int rr = 0; rr < 4; ++rr) {
        const int gr = rowWave + rf * 16 + quad * 4 + rr;
        const float val = acc[rr];
        // exp((val-1)/T) = 2^(val*K1 - K1): one v_fma + one v_exp_f32
        const float ex = __builtin_amdgcn_exp2f(val * K1 - K1);
        if (MODE == 0) {
          rsum[rf][rr] += (gr == gc) ? 0.0f : ex;   // mask self-similarity
        } else if (MODE == 2) {
          rsum[rf][rr] += ex;                       // positive counted once
          if (gc == (gr ^ BHALF)) posv[gr] = val;   // record positive sim
        } else {
          rsum[rf][rr] += ex;
        }
      }
    }
  }
}

// ---------------------------------------------------------------------------
// Kernel 2: full-matrix sim + exp row-sums, zero atomics.
// Grid (16, 32): x = col chunk g (4 strips of 128 cols), y = row block r
// (256 rows). 512 blocks = exactly 2 blocks/CU (LDS: 2 x 64 KB = 128 KB).
// Block: 4 waves; wave w owns rows [r*256 + w*64, +64), A register-resident
// (16 x bf16x8 = 64 VGPR). B strips double-buffered in LDS via
// global_load_lds; stage(s+1) -> compute(s) -> __syncthreads (drains vmcnt).
// Row sums -> direct store partial[g*NROW + row]; finalize sums 16 chunks.
// ---------------------------------------------------------------------------
__global__ __launch_bounds__(256, 2) void sim_kernel(
    const ushort* __restrict__ e, float* __restrict__ partial,
    float* __restrict__ posv) {
  const int g = blockIdx.x;
  const int r = blockIdx.y;

  __shared__ ushort Bs[2][128 * 128] __attribute__((aligned(16)));

  const int tid  = threadIdx.x;
  const int wave = tid >> 6;
  const int lane = tid & 63;
  const int n    = lane & 15;
  const int quad = lane >> 4;

  // Per-lane swizzled LDS chunk offsets (ushort units):
  // global chunk (quad + 4*kk) of row (..n) lives at chunk ^ (n&7).
  int chunkOff[4];
#pragma unroll
  for (int kk = 0; kk < 4; ++kk)
    chunkOff[kk] = (((quad + 4 * kk) ^ (n & 7)) * 8);

  // A fragments: 4 row-frags x 4 k-steps, register-resident (64 rows/wave).
  bf16x8 a_frag[4][4];
  const int rowWave = r * 256 + wave * 64;
#pragma unroll
  for (int rf = 0; rf < 4; ++rf) {
    const ushort* rp = e + (size_t)(rowWave + rf * 16 + n) * DIM + quad * 8;
#pragma unroll
    for (int kk = 0; kk < 4; ++kk)
      a_frag[rf][kk] = *(const bf16x8*)(rp + kk * 32);
  }

  float rsum[4][4] = {{0.f, 0.f, 0.f, 0.f},
                      {0.f, 0.f, 0.f, 0.f},
                      {0.f, 0.f, 0.f, 0.f},
                      {0.f, 0.f, 0.f, 0.f}};

  // Prologue: stage strip 0.
  stage_strip(e + (size_t)(g * 4) * 128 * DIM, Bs[0], wave, lane);
  __syncthreads();

#pragma unroll 1
  for (int s = 0; s < 4; ++s) {
    if (s < 3)  // issue next strip's DMA; it lands under this phase's compute
      stage_strip(e + (size_t)(g * 4 + s + 1) * 128 * DIM, Bs[(s + 1) & 1],
                  wave, lane);
    const ushort* buf = Bs[s & 1];
    const int t = g * 4 + s;              // global 128-col strip index
    const int colBase = t * 128;
    if ((t >> 1) == r)                    // cols within block's own rows
      sweep_strip<0>(buf, a_frag, rsum, posv, chunkOff, n, quad, rowWave,
                     colBase);
    else if ((t >> 1) == (r ^ 16))        // partner strip (col = row ^ 4096)
      sweep_strip<2>(buf, a_frag, rsum, posv, chunkOff, n, quad, rowWave,
                     colBase);
    else
      sweep_strip<1>(buf, a_frag, rsum, posv, chunkOff, n, quad, rowWave,
                     colBase);
    if (s < 3) __syncthreads();  // drains vmcnt(0): next buffer ready
  }

  // Row sums: reduce across the 16 col-lanes, direct store (no atomics).
#pragma unroll
  for (int rf = 0; rf < 4; ++rf)
#pragma unroll
    for (int rr = 0; rr < 4; ++rr) {
      float v = rsum[rf][rr];
      v += __shfl_xor(v, 1);
      v += __shfl_xor(v, 2);
      v += __shfl_xor(v, 4);
      v += __shfl_xor(v, 8);
      if (n == 0)
        partial[g * NROW + rowWave + rf * 16 + quad * 4 + rr] = v;
    }
}

// ---------------------------------------------------------------------------
// Kernel 3: S_i = sum_g partial[g][i]; loss_i = log(S_i + exp((pos-1)/T))
//           + (1-pos_i)/T ; out = mean (atomic partials).
// ---------------------------------------------------------------------------
__global__ __launch_bounds__(256) void finalize_kernel(
    const float* __restrict__ partial, const float* __restrict__ posv,
    float* __restrict__ out) {
  __shared__ float red[4];
  const int i = blockIdx.x * 256 + threadIdx.x;
  float S = 0.0f;
#pragma unroll
  for (int gg = 0; gg < NCHUNK; ++gg) S += partial[gg * NROW + i];
  const float p = posv[i];
  const float l =
      __logf(S + __builtin_amdgcn_exp2f(p * K1 - K1)) + (1.0f - p) * INV_T;
  float v = l;
#pragma unroll
  for (int off = 32; off > 0; off >>= 1) v += __shfl_down(v, off);
  if ((threadIdx.x & 63) == 0) red[threadIdx.x >> 6] = v;
  __syncthreads();
  if (threadIdx.x == 0)
    atomicAdd(out, (red[0] + red[1] + red[2] + red[3]) * (1.0f / NROW));
}

// ---------------------------------------------------------------------------
extern "C" void kernel_launch(void* const* d_in, const int* in_sizes, int n_in,
                              void* d_out, int out_size, void* d_ws, size_t ws_size,
                              hipStream_t stream) {
  const float* v1 = (const float*)d_in[0];
  const float* v2 = (const float*)d_in[1];
  float* out = (float*)d_out;

  __hip_bfloat16* e = (__hip_bfloat16*)d_ws;          // NROW*DIM bf16 (2 MB)
  float* partial = (float*)(e + (size_t)NROW * DIM);  // NCHUNK*NROW floats
  float* posv    = partial + (size_t)NCHUNK * NROW;   // NROW floats

  normalize_kernel<<<NROW / 4, 256, 0, stream>>>(v1, v2, e, out);
  dim3 grid(NCHUNK, 32);
  sim_kernel<<<grid, 256, 0, stream>>>((const ushort*)e, partial, posv);
  finalize_kernel<<<32, 256, 0, stream>>>(partial, posv, out);
}

// Round 4
// 90.047 us; speedup vs baseline: 1.0139x; 1.0139x over previous
//
#include <hip/hip_runtime.h>
#include <hip/hip_bf16.h>
#include <math.h>

// Problem constants (fixed by reference setup_inputs)
#define BHALF 4096          // B
#define NROW 8192           // 2B
#define DIM 128             // D
#define INV_T 10.0f         // 1/temperature
#define K1 14.4269504088896f  // INV_T*log2(e): exp((v-1)*10) = 2^(v*K1 - K1)

typedef short bf16x8 __attribute__((ext_vector_type(8)));   // 8 bf16 = 4 VGPRs
typedef float f32x4  __attribute__((ext_vector_type(4)));   // C/D frag

typedef const __attribute__((address_space(1))) void ga_void;
typedef __attribute__((address_space(3))) void ls_void;

// ---------------------------------------------------------------------------
// Kernel 1: row-normalize concat(view1, view2) -> e_bf16 (NROW x DIM);
// zero d_out and the two never-written partial slices. One wave per row.
// ---------------------------------------------------------------------------
__global__ __launch_bounds__(256) void normalize_kernel(
    const float* __restrict__ v1, const float* __restrict__ v2,
    __hip_bfloat16* __restrict__ e, float* __restrict__ rowpart,
    float* __restrict__ colpart, float* __restrict__ out) {
  int row  = blockIdx.x * 4 + (threadIdx.x >> 6);
  int lane = threadIdx.x & 63;
  const float* src = (row < BHALF) ? (v1 + (size_t)row * DIM)
                                   : (v2 + (size_t)(row - BHALF) * DIM);
  float2 x = ((const float2*)src)[lane];
  float ss = x.x * x.x + x.y * x.y;
#pragma unroll
  for (int off = 32; off > 0; off >>= 1) ss += __shfl_down(ss, off);
  ss = __shfl(ss, 0);
  float s = 1.0f / fmaxf(sqrtf(ss), 1e-8f);
  ((__hip_bfloat162*)(e + (size_t)row * DIM))[lane] =
      __float22bfloat162_rn(make_float2(x.x * s, x.y * s));
  // Zero the two partial slices no sim block writes:
  //   rowpart[32][4096..8192)  (rows >=4096 have no d=32 row-tile)
  //   colpart[31][0..4096)     (cols <4096 have no d=32 col-tile)
  const int t = blockIdx.x * 256 + threadIdx.x;
  if (t < 4096)      rowpart[(size_t)32 * NROW + 4096 + t] = 0.0f;
  else if (t < 8192) colpart[(size_t)31 * NROW + (t - 4096)] = 0.0f;
  if (t == 0) out[0] = 0.0f;
}

// ---------------------------------------------------------------------------
// Stage one 128-col strip of e (128 rows x 256 B) into LDS via
// global_load_lds(16B). LDS layout: [128 rows][16 chunks of 16B], chunk index
// XOR-swizzled by (row&7): ds_read_b128 of a fixed global chunk across rows
// spreads over 8 bank-quads. Rule #21: LDS dest LINEAR (wave-uniform base +
// lane*16); swizzle applied by permuting the per-lane GLOBAL source chunk
// (XOR involution). Each wave stages 32 rows. (Verified in R7/R8.)
// ---------------------------------------------------------------------------
__device__ __forceinline__ void stage_strip(const ushort* __restrict__ eC,
                                            ushort* BsBuf, int wave, int lane) {
#pragma unroll
  for (int j = 0; j < 8; ++j) {
    const int row    = wave * 32 + j * 4 + (lane >> 4);
    const int chunkp = lane & 15;                 // LDS chunk this lane fills
    const int gchunk = chunkp ^ (row & 7);        // global chunk it must hold
    const ushort* g  = eC + row * DIM + gchunk * 8;
    ushort* l        = BsBuf + (wave * 32 + j * 4) * 128;  // wave-uniform base
    __builtin_amdgcn_global_load_lds((ga_void*)g, (ls_void*)l, 16, 0, 0);
  }
}

// ---------------------------------------------------------------------------
// Symmetric MFMA sweep over one 128x128 tile (rows: strip r, cols: strip c).
// MODE 0: diagonal tile (r==c): mask col==row; row-sums only (tile is
//         self-symmetric, col contributions appear as other rows' sums).
// MODE 1: off-diag tile: each exp feeds row-sum AND col-sum (symmetry).
// MODE 2: partner tile (c == r^32): local diagonal = positives, weight 2
//         (denominator col-0 term + unmasked negative), posv for BOTH rows.
// Col-sums go to LDS colred[wave][col] (per-sub store, unique slot) — the
// caller cross-wave reduces and direct-stores. ZERO atomics (R0->R7 showed
// ~1.3M device atomics over 8KB of addresses serialize ~15us at the TCC).
// ---------------------------------------------------------------------------
template <int MODE>
__device__ __forceinline__ void sweep_tile(
    const ushort* __restrict__ Bs, const bf16x8 (&a_frag)[2][4],
    float (&rsum)[2][4], float (*colred)[128], float* __restrict__ posv,
    const int (&chunkOff)[4], int wave, int lane, int n, int quad,
    int rowStrip, int colStrip) {
  const int colBase = colStrip * 128;
  for (int sub = 0; sub < 8; ++sub) {
    const ushort* bp = Bs + (sub * 16 + n) * 128;
    bf16x8 b[4];
#pragma unroll
    for (int kk = 0; kk < 4; ++kk) b[kk] = *(const bf16x8*)(bp + chunkOff[kk]);
    float csum = 0.0f;
    const int lc = sub * 16 + n;
#pragma unroll
    for (int rf = 0; rf < 2; ++rf) {
      f32x4 acc = {0.f, 0.f, 0.f, 0.f};
#pragma unroll
      for (int kk = 0; kk < 4; ++kk)
        acc = __builtin_amdgcn_mfma_f32_16x16x32_bf16(a_frag[rf][kk], b[kk],
                                                      acc, 0, 0, 0);
      // C layout: row = quad*4 + reg, col = lane&15 (m89/m91 verified).
#pragma unroll
      for (int rr = 0; rr < 4; ++rr) {
        const int lr = wave * 32 + rf * 16 + quad * 4 + rr;
        const float val = acc[rr];
        // exp((val-1)/T) = 2^(val*K1 - K1): one v_fma + one v_exp_f32
        const float ex = __builtin_amdgcn_exp2f(val * K1 - K1);
        if (MODE == 0) {
          rsum[rf][rr] += (lr == lc) ? 0.0f : ex;       // mask true diagonal
        } else if (MODE == 1) {
          rsum[rf][rr] += ex;
          csum += ex;
        } else {                                        // partner tile
          const bool hit = (lr == lc);
          const float w = hit ? 2.0f : 1.0f;
          rsum[rf][rr] += w * ex;
          csum += w * ex;
          if (hit) {
            posv[rowStrip * 128 + lr] = val;            // row i (<4096)
            posv[colBase + lc] = val;                   // partner j = i^4096
          }
        }
      }
    }
    if (MODE != 0) {
      // col-sum over this wave's 32 rows -> LDS slot (no atomic).
      csum += __shfl_xor(csum, 16);
      csum += __shfl_xor(csum, 32);
      if (lane < 16) colred[wave][lc] = csum;
    }
  }
}

// ---------------------------------------------------------------------------
// Kernel 2: symmetric sim + exp-sum partials, zero atomics.
// Grid (64, 33): x = row strip r, y = cyclic offset d; col strip c=(r+d)&63;
// d=32 valid only for r<32 (partner pairing). 2080 live blocks; LDS
// 32KB+2KB -> 4 blocks/CU = 4 waves/SIMD (R8 lesson: waves/SIMD dominate).
// Row sums -> rowpart[d][row] (unique slot per block). Col sums -> LDS
// colred cross-wave reduce -> colpart[d-1][col] (unique slot per block).
// ---------------------------------------------------------------------------
__global__ __launch_bounds__(256, 4) void sim_kernel(
    const ushort* __restrict__ e, float* __restrict__ rowpart,
    float* __restrict__ colpart, float* __restrict__ posv) {
  const int r = blockIdx.x;
  const int d = blockIdx.y;
  if (d == 32 && r >= 32) return;   // uniform: whole block exits, no barrier hazard
  const int c = (r + d) & 63;

  __shared__ ushort Bs[128 * 128] __attribute__((aligned(16)));
  __shared__ float colred[4][128];

  const int tid  = threadIdx.x;
  const int wave = tid >> 6;
  const int lane = tid & 63;
  const int n    = lane & 15;
  const int quad = lane >> 4;

  // Per-lane swizzled LDS chunk offsets (ushort units):
  // global chunk (quad + 4*kk) of row (..n) lives at chunk ^ (n&7).
  int chunkOff[4];
#pragma unroll
  for (int kk = 0; kk < 4; ++kk)
    chunkOff[kk] = (((quad + 4 * kk) ^ (n & 7)) * 8);

  // Stage col strip (DMA flies under the A-frag loads below).
  stage_strip(e + (size_t)c * 128 * DIM, Bs, wave, lane);

  // A fragments: 2 row-frags x 4 k-steps, register-resident.
  bf16x8 a_frag[2][4];
  const int rowWave = r * 128 + wave * 32;
#pragma unroll
  for (int rf = 0; rf < 2; ++rf) {
    const ushort* rp = e + (size_t)(rowWave + rf * 16 + n) * DIM + quad * 8;
#pragma unroll
    for (int kk = 0; kk < 4; ++kk)
      a_frag[rf][kk] = *(const bf16x8*)(rp + kk * 32);
  }

  float rsum[2][4] = {{0.f, 0.f, 0.f, 0.f}, {0.f, 0.f, 0.f, 0.f}};
  __syncthreads();   // drains vmcnt(0): Bs ready

  if (d == 0)
    sweep_tile<0>(Bs, a_frag, rsum, colred, posv, chunkOff, wave, lane, n,
                  quad, r, c);
  else if (d == 32)
    sweep_tile<2>(Bs, a_frag, rsum, colred, posv, chunkOff, wave, lane, n,
                  quad, r, c);
  else
    sweep_tile<1>(Bs, a_frag, rsum, colred, posv, chunkOff, wave, lane, n,
                  quad, r, c);

  // Row sums: reduce across the 16 col-lanes, direct store (unique slot).
#pragma unroll
  for (int rf = 0; rf < 2; ++rf)
#pragma unroll
    for (int rr = 0; rr < 4; ++rr) {
      float v = rsum[rf][rr];
      v += __shfl_xor(v, 1);
      v += __shfl_xor(v, 2);
      v += __shfl_xor(v, 4);
      v += __shfl_xor(v, 8);
      if (n == 0)
        rowpart[(size_t)d * NROW + rowWave + rf * 16 + quad * 4 + rr] = v;
    }

  // Col sums: cross-wave reduce in LDS, direct store (unique slot per d).
  if (d != 0) {
    __syncthreads();
    if (tid < 128) {
      float s = colred[0][tid] + colred[1][tid] + colred[2][tid] +
                colred[3][tid];
      colpart[(size_t)(d - 1) * NROW + c * 128 + tid] = s;
    }
  }
}

// ---------------------------------------------------------------------------
// Kernel 3: S_i = sum_d rowpart[d][i] + sum_s colpart[s][i];
// loss_i = log(S_i) + (1-pos_i)/T ; out = mean (32 atomic partials).
// ---------------------------------------------------------------------------
__global__ __launch_bounds__(256) void finalize_kernel(
    const float* __restrict__ rowpart, const float* __restrict__ colpart,
    const float* __restrict__ posv, float* __restrict__ out) {
  __shared__ float red[4];
  const int i = blockIdx.x * 256 + threadIdx.x;
  float S = 0.0f;
#pragma unroll
  for (int dd = 0; dd < 33; ++dd) S += rowpart[(size_t)dd * NROW + i];
#pragma unroll
  for (int ss = 0; ss < 32; ++ss) S += colpart[(size_t)ss * NROW + i];
  float l = __logf(S) + (1.0f - posv[i]) * INV_T;
#pragma unroll
  for (int off = 32; off > 0; off >>= 1) l += __shfl_down(l, off);
  if ((threadIdx.x & 63) == 0) red[threadIdx.x >> 6] = l;
  __syncthreads();
  if (threadIdx.x == 0)
    atomicAdd(out, (red[0] + red[1] + red[2] + red[3]) * (1.0f / NROW));
}

// ---------------------------------------------------------------------------
extern "C" void kernel_launch(void* const* d_in, const int* in_sizes, int n_in,
                              void* d_out, int out_size, void* d_ws, size_t ws_size,
                              hipStream_t stream) {
  const float* v1 = (const float*)d_in[0];
  const float* v2 = (const float*)d_in[1];
  float* out = (float*)d_out;

  __hip_bfloat16* e = (__hip_bfloat16*)d_ws;          // NROW*DIM bf16 (2 MB)
  float* rowpart = (float*)(e + (size_t)NROW * DIM);  // 33*NROW floats
  float* colpart = rowpart + (size_t)33 * NROW;       // 32*NROW floats
  float* posv    = colpart + (size_t)32 * NROW;       // NROW floats

  normalize_kernel<<<NROW / 4, 256, 0, stream>>>(v1, v2, e, rowpart, colpart,
                                                 out);
  dim3 grid(64, 33);
  sim_kernel<<<grid, 256, 0, stream>>>((const ushort*)e, rowpart, colpart,
                                       posv);
  finalize_kernel<<<32, 256, 0, stream>>>(rowpart, colpart, posv, out);
}